// Round 3
// baseline (150.740 us; speedup 1.0000x reference)
//
#include <hip/hip_runtime.h>

typedef short bshort8 __attribute__((ext_vector_type(8)));
typedef float f32x4 __attribute__((ext_vector_type(4)));

#define DEVFN static __device__ __forceinline__

DEVFN unsigned short f2bf(float f) {
    union { float f; unsigned u; } v; v.f = f;
    unsigned r = (v.u + 0x7FFFu + ((v.u >> 16) & 1u)) >> 16;
    return (unsigned short)r;
}

DEVFN unsigned cvt_pk_bf16(float a, float b) {
    unsigned r;
    asm("v_cvt_pk_bf16_f32 %0, %1, %2" : "=v"(r) : "v"(a), "v"(b));
    return r;
}

DEVFN float exp2_fast(float x) {
    float r;
    asm("v_exp_f32 %0, %1" : "=v"(r) : "v"(x));
    return r;
}

// XOR swizzle for 128-byte LDS rows (8 chunks of 16B)
DEVFN int swzf(int row) { return (row & 7) ^ ((row >> 3) & 7); }
// XOR swizzle for 64-byte LDS rows (4 chunks of 16B)
DEVFN int swzf2(int row) { return (row & 3) ^ ((row >> 2) & 3); }

#define GLDS16(g, l)                                                            \
    __builtin_amdgcn_global_load_lds(                                           \
        (__attribute__((address_space(1))) void*)(g),                           \
        (__attribute__((address_space(3))) void*)(l), 16, 0, 0)

// ---------------------------------------------------------------- prep kernels

__global__ void cast_x_kernel(const float* __restrict__ x,
                              unsigned short* __restrict__ xb, int n4) {
    int i = blockIdx.x * blockDim.x + threadIdx.x;
    int stride = gridDim.x * blockDim.x;
    for (; i < n4; i += stride) {
        float4 v = ((const float4*)x)[i];
        ushort4 o;
        o.x = f2bf(v.x); o.y = f2bf(v.y); o.z = f2bf(v.z); o.w = f2bf(v.w);
        ((ushort4*)xb)[i] = o;
    }
}

// src is K x N (f32, row-major). dst is N x K (bf16, row-major).
__global__ void transpose_cast_kernel(const float* __restrict__ src,
                                      unsigned short* __restrict__ dst,
                                      int K, int N) {
    __shared__ float tile[32][33];
    int n0 = blockIdx.x * 32, k0 = blockIdx.y * 32;
    int tx = threadIdx.x, ty = threadIdx.y; // (32, 8)
#pragma unroll
    for (int i = 0; i < 4; i++)
        tile[ty + i * 8][tx] = src[(size_t)(k0 + ty + i * 8) * N + n0 + tx];
    __syncthreads();
#pragma unroll
    for (int i = 0; i < 4; i++)
        dst[(size_t)(n0 + ty + i * 8) * K + k0 + tx] = f2bf(tile[tx][ty + i * 8]);
}

__global__ void rope_table_kernel(float2* __restrict__ cs) {
    int idx = blockIdx.x * 256 + threadIdx.x; // < 2048*32
    int t = idx >> 5, i = idx & 31;
    float inv_freq = powf(10000.0f, -(float)i / 32.0f);
    float a = (float)t * inv_freq;
    cs[idx] = make_float2(cosf(a), sinf(a));
}

// Vb[m][t][d] (2048x64) -> Vt[m][d][t] (64x2048), m = b*4+kvh
__global__ void transpose_v_kernel(const unsigned short* __restrict__ Vb,
                                   unsigned short* __restrict__ Vt) {
    __shared__ unsigned short tile[64][66];
    int t0 = blockIdx.x * 64, m = blockIdx.y;
    int tx = threadIdx.x, ty = threadIdx.y; // (32, 8)
    const unsigned short* src = Vb + (size_t)m * 2048 * 64;
    unsigned short* dst = Vt + (size_t)m * 64 * 2048;
#pragma unroll
    for (int i = 0; i < 8; i++) {
        int t = ty + i * 8;
        *(ushort2*)&tile[t][tx * 2] =
            *(const ushort2*)(src + (size_t)(t0 + t) * 64 + tx * 2);
    }
    __syncthreads();
#pragma unroll
    for (int i = 0; i < 8; i++) {
        int d = ty + i * 8;
        ushort2 o;
        o.x = tile[tx * 2][d];
        o.y = tile[tx * 2 + 1][d];
        *(ushort2*)(dst + (size_t)d * 2048 + t0 + tx * 2) = o;
    }
}

// ------------------------------------------------------------- QKV GEMM + RoPE
// C = Xb(4096x1024) @ W(1024x1536) with W supplied transposed (wt: 1536x1024).
// n in [0,1024): Q (RoPE + 0.125*log2e scale); [1024,1280): K (RoPE); [1280,1536): V.

__global__ __launch_bounds__(256) void gemm_qkv_kernel(
    const unsigned short* __restrict__ xb, const unsigned short* __restrict__ wt,
    const float2* __restrict__ cs, unsigned short* __restrict__ Qb,
    unsigned short* __restrict__ Kb, unsigned short* __restrict__ Vb) {
    __shared__ char smem[16384];
    char* As = smem;
    char* Bs = smem + 8192;
    const int tid = threadIdx.x;
    const int lane = tid & 63, w = tid >> 6;
    const int wm = w >> 1, wn = w & 1;
    const int m0 = blockIdx.y * 128, n0 = blockIdx.x * 128;
    const int l15 = lane & 15, g = lane >> 4;

    const int srow = tid >> 2;
    const int sc0 = (tid & 3) ^ swzf2(srow);
    const int sc1 = (tid & 3) ^ swzf2(srow + 64);
    const unsigned short* aRow0 = xb + (size_t)(m0 + srow) * 1024 + sc0 * 8;
    const unsigned short* aRow1 = xb + (size_t)(m0 + srow + 64) * 1024 + sc1 * 8;
    const unsigned short* bRow0 = wt + (size_t)(n0 + srow) * 1024 + sc0 * 8;
    const unsigned short* bRow1 = wt + (size_t)(n0 + srow + 64) * 1024 + sc1 * 8;

    f32x4 acc[4][4] = {};
    for (int kt = 0; kt < 32; kt++) {
        __syncthreads();
        GLDS16(aRow0 + kt * 32, As + tid * 16);
        GLDS16(aRow1 + kt * 32, As + tid * 16 + 4096);
        GLDS16(bRow0 + kt * 32, Bs + tid * 16);
        GLDS16(bRow1 + kt * 32, Bs + tid * 16 + 4096);
        __syncthreads();
        bshort8 af[4], bf[4];
#pragma unroll
        for (int fm = 0; fm < 4; fm++) {
            int row = wm * 64 + fm * 16 + l15;
            af[fm] = *(const bshort8*)(As + row * 64 + ((g ^ swzf2(row)) << 4));
        }
#pragma unroll
        for (int fn = 0; fn < 4; fn++) {
            int row = wn * 64 + fn * 16 + l15;
            bf[fn] = *(const bshort8*)(Bs + row * 64 + ((g ^ swzf2(row)) << 4));
        }
#pragma unroll
        for (int fm = 0; fm < 4; fm++)
#pragma unroll
            for (int fn = 0; fn < 4; fn++)
                acc[fm][fn] = __builtin_amdgcn_mfma_f32_16x16x32_bf16(
                    af[fm], bf[fn], acc[fm][fn], 0, 0, 0);
    }

    const bool isV = (n0 >= 1280);
    const bool isK = (n0 >= 1024) && !isV;
#pragma unroll
    for (int fm = 0; fm < 4; fm++) {
#pragma unroll
        for (int r = 0; r < 4; r++) {
            int m = m0 + wm * 64 + fm * 16 + g * 4 + r;
            int b = m >> 11, t = m & 2047;
            if (isV) {
#pragma unroll
                for (int fn = 0; fn < 4; fn++) {
                    int n = n0 + wn * 64 + fn * 16 + l15;
                    int d = n & 63, vh = (n - 1280) >> 6;
                    Vb[((size_t)(b * 4 + vh) * 2048 + t) * 64 + d] =
                        f2bf(acc[fm][fn][r]);
                }
            } else {
                float2 c0 = cs[t * 32 + l15];
                float2 c1 = cs[t * 32 + 16 + l15];
#pragma unroll
                for (int fn = 0; fn < 4; fn++) {
                    int n = n0 + wn * 64 + fn * 16 + l15;
                    int d = n & 63;
                    float val = acc[fm][fn][r];
                    float pair = acc[fm][fn ^ 2][r];
                    float rot = (fn < 2) ? -pair : pair;
                    float2 cc = (fn & 1) ? c1 : c0;
                    float o = val * cc.x + rot * cc.y;
                    if (isK) {
                        int kh = (n - 1024) >> 6;
                        Kb[((size_t)(b * 4 + kh) * 2048 + t) * 64 + d] = f2bf(o);
                    } else {
                        o *= 0.1803368801111504f;  // 0.125 * log2(e)
                        int h = n >> 6;
                        Qb[((size_t)(b * 16 + h) * 2048 + t) * 64 + d] = f2bf(o);
                    }
                }
            }
        }
    }
}

// ------------------------------------------------------------- flash attention
// Swapped-QK^T. One qt per block (heavy-first), 4 waves x 16 q-rows, KV tile 64,
// double-buffered. Softmax in base-2 (log2e folded into Q scale).
// LDS map: [0,8K) Q/P strips, K bufs at 0x2000/0x4000, V bufs at 0x6000/0x8000.

__global__ __launch_bounds__(256) void attn_kernel(
    const unsigned short* __restrict__ Qb, const unsigned short* __restrict__ Kb,
    const unsigned short* __restrict__ Vt, unsigned short* __restrict__ Ob) {
    __shared__ char smem[40960];
    const int tid = threadIdx.x, lane = tid & 63, w = tid >> 6;
    const int l15 = lane & 15, g = lane >> 4;
    const int qt = 31 - blockIdx.x;  // heavy blocks dispatched first
    const int h = blockIdx.y, b = blockIdx.z;
    const int kvh = h >> 2;
    const int qs = qt * 64;

    const unsigned short* Kbase = Kb + (size_t)(b * 4 + kvh) * 2048 * 64;
    const unsigned short* Vbase = Vt + (size_t)(b * 4 + kvh) * 64 * 2048;
    const unsigned short* Qhead = Qb + (size_t)(b * 16 + h) * 2048 * 64;

    const int srow8 = lane >> 3;  // 0..7
    const int sci = lane & 7;     // chunk 0..7
    const int s = (l15 & 7) ^ (l15 >> 3);  // row swizzle key (row & 15 based)
    const int strip = w * 2048;

    // ---- loop-invariant LDS addresses
    const int rowb = l15 * 128 + ((g ^ s) << 4);
    const int Aq0 = strip + rowb;          // Q read (imm 0), Aq1 = ^64
    int Ak0 = 0x2000 + rowb;               // K read bases (imm fn*2048)
    int Ak1 = Ak0 ^ 64;
    int Av0 = 0x6000 + rowb;               // V read bases (imm fd*2048)
    int Av1 = Av0 ^ 64;
    // P store/load (per-wave strip; kvpos = g*16 + fn*4 + r layout)
    const int pw0 = strip + l15 * 128 + (((2 * g) ^ s) << 4);
    const int pw1 = strip + l15 * 128 + (((2 * g + 1) ^ s) << 4);
    const int byteA0 = ((2 * g) & 3) * 32 + (g >> 1) * 8;
    const int byteB0 = ((2 * g + 1) & 3) * 32 + (g >> 1) * 8;
    const int prA0 = strip + l15 * 128 + (((byteA0 >> 4) ^ s) << 4) + (byteA0 & 15);
    const int prB0 = strip + l15 * 128 + (((byteB0 >> 4) ^ s) << 4) + (byteB0 & 15);

    // ---- staging geometry
    const int lc0 = sci ^ srow8;       // it=0 source chunk
    const int lc1 = sci ^ srow8 ^ 1;   // it=1
    const int r0 = w * 16 + srow8, r1 = w * 16 + 8 + srow8;

    // prologue: stage Q + K tile0 + V tile0
    GLDS16(Qhead + (size_t)(qs + r0) * 64 + lc0 * 8, smem + strip + lane * 16);
    GLDS16(Qhead + (size_t)(qs + r1) * 64 + lc1 * 8, smem + strip + lane * 16 + 1024);
    GLDS16(Kbase + (size_t)r0 * 64 + lc0 * 8, smem + 0x2000 + strip + lane * 16);
    GLDS16(Kbase + (size_t)r1 * 64 + lc1 * 8, smem + 0x2000 + strip + lane * 16 + 1024);
    GLDS16(Vbase + (size_t)r0 * 2048 + lc0 * 8, smem + 0x6000 + strip + lane * 16);
    GLDS16(Vbase + (size_t)r1 * 2048 + lc1 * 8, smem + 0x6000 + strip + lane * 16 + 1024);
    __syncthreads();

    bshort8 qf0 = *(const bshort8*)(smem + Aq0);
    bshort8 qf1 = *(const bshort8*)(smem + (Aq0 ^ 64));

    // prefetch pointers (next tile = kv0 64)
    const unsigned short* gk0 = Kbase + (size_t)(64 + r0) * 64 + lc0 * 8;
    const unsigned short* gk1 = Kbase + (size_t)(64 + r1) * 64 + lc1 * 8;
    const unsigned short* gv0 = Vbase + (size_t)r0 * 2048 + 64 + lc0 * 8;
    const unsigned short* gv1 = Vbase + (size_t)r1 * 2048 + 64 + lc1 * 8;
    int kdst = 0x4000 + strip + lane * 16;
    int vdst = 0x8000 + strip + lane * 16;

    float m_run = -1e30f, l_run = 0.f;
    f32x4 O[4] = {};
    const int qlocal = w * 16 + l15;

    for (int kt = 0; kt <= qt; kt++) {
        if (kt < qt) {
            GLDS16(gk0, smem + kdst);
            GLDS16(gk1, smem + kdst + 1024);
            GLDS16(gv0, smem + vdst);
            GLDS16(gv1, smem + vdst + 1024);
            gk0 += 4096; gk1 += 4096; gv0 += 64; gv1 += 64;
        }
        // S^T[kv][q] = mfma(K, Q): lane holds kv = 16fn+4g+r, q = l15
        f32x4 S[4];
#pragma unroll
        for (int fn = 0; fn < 4; fn++) {
            bshort8 k0 = *(const bshort8*)(smem + Ak0 + fn * 2048);
            bshort8 k1 = *(const bshort8*)(smem + Ak1 + fn * 2048);
            f32x4 a = {};
            a = __builtin_amdgcn_mfma_f32_16x16x32_bf16(k0, qf0, a, 0, 0, 0);
            a = __builtin_amdgcn_mfma_f32_16x16x32_bf16(k1, qf1, a, 0, 0, 0);
            S[fn] = a;
        }
        if (kt == qt) {  // causal mask on the diagonal tile
#pragma unroll
            for (int fn = 0; fn < 4; fn++)
#pragma unroll
                for (int r = 0; r < 4; r++)
                    if (fn * 16 + g * 4 + r > qlocal) S[fn][r] = -1e30f;
        }
        // online softmax (base-2), row q = l15 spread over 4 g-groups
        float mt = -1e30f;
#pragma unroll
        for (int fn = 0; fn < 4; fn++)
#pragma unroll
            for (int r = 0; r < 4; r++) mt = fmaxf(mt, S[fn][r]);
        mt = fmaxf(mt, __shfl_xor(mt, 16));
        mt = fmaxf(mt, __shfl_xor(mt, 32));
        float mn = fmaxf(m_run, mt);
        float alpha = exp2_fast(m_run - mn);
        m_run = mn;
        float p[4][4];
        float rs = 0.f;
#pragma unroll
        for (int fn = 0; fn < 4; fn++)
#pragma unroll
            for (int r = 0; r < 4; r++) {
                p[fn][r] = exp2_fast(S[fn][r] - mn);
                rs += p[fn][r];
            }
        rs += __shfl_xor(rs, 16);
        rs += __shfl_xor(rs, 32);
        l_run = l_run * alpha + rs;
#pragma unroll
        for (int fd = 0; fd < 4; fd++) O[fd] *= alpha;
        // P -> LDS: two b128 writes (kvpos layout, conflict-free)
        int4 w0v, w1v;
        w0v.x = cvt_pk_bf16(p[0][0], p[0][1]);
        w0v.y = cvt_pk_bf16(p[0][2], p[0][3]);
        w0v.z = cvt_pk_bf16(p[1][0], p[1][1]);
        w0v.w = cvt_pk_bf16(p[1][2], p[1][3]);
        w1v.x = cvt_pk_bf16(p[2][0], p[2][1]);
        w1v.y = cvt_pk_bf16(p[2][2], p[2][3]);
        w1v.z = cvt_pk_bf16(p[3][0], p[3][1]);
        w1v.w = cvt_pk_bf16(p[3][2], p[3][3]);
        *(int4*)(smem + pw0) = w0v;
        *(int4*)(smem + pw1) = w1v;
        asm volatile("s_waitcnt lgkmcnt(0)" ::: "memory");
        __builtin_amdgcn_sched_barrier(0);
        // P load as B-frags: kv = ks*32 + 8g + e
        union PF { int2 d[2]; bshort8 v; };
        PF u0, u1;
        u0.d[0] = *(const int2*)(smem + prA0);
        u0.d[1] = *(const int2*)(smem + prB0);
        u1.d[0] = *(const int2*)(smem + (prA0 ^ 16));
        u1.d[1] = *(const int2*)(smem + (prB0 ^ 16));
        // O^T[d][q] += mfma(V^T, P)
#pragma unroll
        for (int fd = 0; fd < 4; fd++) {
            bshort8 v0 = *(const bshort8*)(smem + Av0 + fd * 2048);
            bshort8 v1 = *(const bshort8*)(smem + Av1 + fd * 2048);
            O[fd] = __builtin_amdgcn_mfma_f32_16x16x32_bf16(v0, u0.v, O[fd], 0, 0, 0);
            O[fd] = __builtin_amdgcn_mfma_f32_16x16x32_bf16(v1, u1.v, O[fd], 0, 0, 0);
        }
        // toggle double buffers
        Ak0 ^= 0x6000; Ak1 ^= 0x6000; Av0 ^= 0xE000; Av1 ^= 0xE000;
        kdst ^= 0x6000; vdst ^= 0xE000;
        if (kt < qt) __syncthreads();
    }

    // epilogue: normalize, transpose through per-wave LDS strip, coalesced store
    float inv = 1.0f / l_run;
#pragma unroll
    for (int fd = 0; fd < 4; fd++)
#pragma unroll
        for (int w2 = 0; w2 < 2; w2++) {
            unsigned word = cvt_pk_bf16(O[fd][2 * w2] * inv, O[fd][2 * w2 + 1] * inv);
            int byte = fd * 32 + g * 8 + w2 * 4;
            *(unsigned*)(smem + strip + l15 * 128 + (((byte >> 4) ^ s) << 4) +
                         (byte & 15)) = word;
        }
    asm volatile("s_waitcnt lgkmcnt(0)" ::: "memory");
    __builtin_amdgcn_sched_barrier(0);
#pragma unroll
    for (int it = 0; it < 2; it++) {
        int r16 = it * 8 + srow8;
        int4 vv = *(const int4*)(smem + strip + r16 * 128 +
                                 ((sci ^ srow8 ^ it) << 4));
        int t = qs + w * 16 + r16;
        *(int4*)(Ob + (size_t)(b * 2048 + t) * 1024 + h * 64 + sci * 8) = vv;
    }
}

// ------------------------------------------------------------- output GEMM
__global__ __launch_bounds__(256) void gemm_out_kernel(
    const unsigned short* __restrict__ ab, const unsigned short* __restrict__ wot,
    float* __restrict__ out) {
    __shared__ char smem[16384];
    char* As = smem;
    char* Bs = smem + 8192;
    const int tid = threadIdx.x;
    const int lane = tid & 63, w = tid >> 6;
    const int wm = w >> 1, wn = w & 1;
    const int m0 = blockIdx.y * 128, n0 = blockIdx.x * 128;
    const int l15 = lane & 15, g = lane >> 4;

    const int srow = tid >> 2;
    const int sc0 = (tid & 3) ^ swzf2(srow);
    const int sc1 = (tid & 3) ^ swzf2(srow + 64);
    const unsigned short* aRow0 = ab + (size_t)(m0 + srow) * 1024 + sc0 * 8;
    const unsigned short* aRow1 = ab + (size_t)(m0 + srow + 64) * 1024 + sc1 * 8;
    const unsigned short* bRow0 = wot + (size_t)(n0 + srow) * 1024 + sc0 * 8;
    const unsigned short* bRow1 = wot + (size_t)(n0 + srow + 64) * 1024 + sc1 * 8;

    f32x4 acc[4][4] = {};
    for (int kt = 0; kt < 32; kt++) {
        __syncthreads();
        GLDS16(aRow0 + kt * 32, As + tid * 16);
        GLDS16(aRow1 + kt * 32, As + tid * 16 + 4096);
        GLDS16(bRow0 + kt * 32, Bs + tid * 16);
        GLDS16(bRow1 + kt * 32, Bs + tid * 16 + 4096);
        __syncthreads();
        bshort8 af[4], bf[4];
#pragma unroll
        for (int fm = 0; fm < 4; fm++) {
            int row = wm * 64 + fm * 16 + l15;
            af[fm] = *(const bshort8*)(As + row * 64 + ((g ^ swzf2(row)) << 4));
        }
#pragma unroll
        for (int fn = 0; fn < 4; fn++) {
            int row = wn * 64 + fn * 16 + l15;
            bf[fn] = *(const bshort8*)(Bs + row * 64 + ((g ^ swzf2(row)) << 4));
        }
#pragma unroll
        for (int fm = 0; fm < 4; fm++)
#pragma unroll
            for (int fn = 0; fn < 4; fn++)
                acc[fm][fn] = __builtin_amdgcn_mfma_f32_16x16x32_bf16(
                    af[fm], bf[fn], acc[fm][fn], 0, 0, 0);
    }
#pragma unroll
    for (int fm = 0; fm < 4; fm++)
#pragma unroll
        for (int r = 0; r < 4; r++) {
            int m = m0 + wm * 64 + fm * 16 + g * 4 + r;
#pragma unroll
            for (int fn = 0; fn < 4; fn++) {
                int n = n0 + wn * 64 + fn * 16 + l15;
                out[(size_t)m * 1024 + n] = acc[fm][fn][r];
            }
        }
}

// ---------------------------------------------------------------- launch

extern "C" void kernel_launch(void* const* d_in, const int* in_sizes, int n_in,
                              void* d_out, int out_size, void* d_ws, size_t ws_size,
                              hipStream_t stream) {
    const float* x = (const float*)d_in[0];
    const float* wq = (const float*)d_in[1];
    const float* wk = (const float*)d_in[2];
    const float* wv = (const float*)d_in[3];
    const float* wo = (const float*)d_in[4];
    float* out = (float*)d_out;
    char* ws = (char*)d_ws;

    unsigned short* xb = (unsigned short*)(ws);                  // 8 MB
    unsigned short* wt = (unsigned short*)(ws + 8388608);        // 3 MB (1536x1024)
    unsigned short* Vtr = (unsigned short*)(ws + 8388608);       // 2 MB (reuses wt after gemm_qkv)
    unsigned short* wot = (unsigned short*)(ws + 11534336);      // 2 MB
    float2* cs = (float2*)(ws + 13631488);                       // 512 KB
    unsigned short* Qb = (unsigned short*)(ws + 14155776);       // 8 MB
    unsigned short* Kb = (unsigned short*)(ws + 22544384);       // 2 MB
    unsigned short* Vb = (unsigned short*)(ws + 24641536);       // 2 MB
    unsigned short* Ob = (unsigned short*)(ws + 26738688);       // 8 MB

    hipLaunchKernelGGL(cast_x_kernel, dim3(2048), dim3(256), 0, stream, x, xb,
                       4194304 / 4);
    hipLaunchKernelGGL(transpose_cast_kernel, dim3(32, 32), dim3(32, 8), 0, stream,
                       wq, wt, 1024, 1024);
    hipLaunchKernelGGL(transpose_cast_kernel, dim3(8, 32), dim3(32, 8), 0, stream,
                       wk, wt + 1024 * 1024, 1024, 256);
    hipLaunchKernelGGL(transpose_cast_kernel, dim3(8, 32), dim3(32, 8), 0, stream,
                       wv, wt + 1280 * 1024, 1024, 256);
    hipLaunchKernelGGL(transpose_cast_kernel, dim3(32, 32), dim3(32, 8), 0, stream,
                       wo, wot, 1024, 1024);
    hipLaunchKernelGGL(rope_table_kernel, dim3(256), dim3(256), 0, stream, cs);
    hipLaunchKernelGGL(gemm_qkv_kernel, dim3(12, 32), dim3(256), 0, stream, xb, wt,
                       cs, Qb, Kb, Vb);
    hipLaunchKernelGGL(transpose_v_kernel, dim3(32, 8), dim3(32, 8), 0, stream, Vb,
                       Vtr);
    hipLaunchKernelGGL(attn_kernel, dim3(32, 16, 2), dim3(256), 0, stream, Qb, Kb,
                       Vtr, Ob);
    hipLaunchKernelGGL(gemm_out_kernel, dim3(8, 32), dim3(256), 0, stream, Ob, wot,
                       out);
}

// Round 4
// 136.957 us; speedup vs baseline: 1.1006x; 1.1006x over previous
//
#include <hip/hip_runtime.h>

typedef short bshort8 __attribute__((ext_vector_type(8)));
typedef float f32x4 __attribute__((ext_vector_type(4)));

#define DEVFN static __device__ __forceinline__

DEVFN unsigned short f2bf(float f) {
    union { float f; unsigned u; } v; v.f = f;
    unsigned r = (v.u + 0x7FFFu + ((v.u >> 16) & 1u)) >> 16;
    return (unsigned short)r;
}

DEVFN float bf2f(unsigned short u) {
    union { unsigned u; float f; } v; v.u = (unsigned)u << 16;
    return v.f;
}

DEVFN unsigned cvt_pk_bf16(float a, float b) {
    unsigned r;
    asm("v_cvt_pk_bf16_f32 %0, %1, %2" : "=v"(r) : "v"(a), "v"(b));
    return r;
}

DEVFN float exp2_fast(float x) {
    float r;
    asm("v_exp_f32 %0, %1" : "=v"(r) : "v"(x));
    return r;
}

// XOR swizzle for 128-byte LDS rows (8 chunks of 16B)
DEVFN int swzf(int row) { return (row & 7) ^ ((row >> 3) & 7); }
// XOR swizzle for 64-byte LDS rows (4 chunks of 16B)
DEVFN int swzf2(int row) { return (row & 3) ^ ((row >> 2) & 3); }

#define GLDS16(g, l)                                                            \
    __builtin_amdgcn_global_load_lds(                                           \
        (__attribute__((address_space(1))) void*)(g),                           \
        (__attribute__((address_space(3))) void*)(l), 16, 0, 0)

// ---------------------------------------------------------------- prep kernels

__global__ void cast_x_kernel(const float* __restrict__ x,
                              unsigned short* __restrict__ xb, int n4) {
    int i = blockIdx.x * blockDim.x + threadIdx.x;
    int stride = gridDim.x * blockDim.x;
    for (; i < n4; i += stride) {
        float4 v = ((const float4*)x)[i];
        ushort4 o;
        o.x = f2bf(v.x); o.y = f2bf(v.y); o.z = f2bf(v.z); o.w = f2bf(v.w);
        ((ushort4*)xb)[i] = o;
    }
}

// src is K x N (f32, row-major). dst is N x K (bf16, row-major).
__global__ void transpose_cast_kernel(const float* __restrict__ src,
                                      unsigned short* __restrict__ dst,
                                      int K, int N) {
    __shared__ float tile[32][33];
    int n0 = blockIdx.x * 32, k0 = blockIdx.y * 32;
    int tx = threadIdx.x, ty = threadIdx.y; // (32, 8)
#pragma unroll
    for (int i = 0; i < 4; i++)
        tile[ty + i * 8][tx] = src[(size_t)(k0 + ty + i * 8) * N + n0 + tx];
    __syncthreads();
#pragma unroll
    for (int i = 0; i < 4; i++)
        dst[(size_t)(n0 + ty + i * 8) * K + k0 + tx] = f2bf(tile[tx][ty + i * 8]);
}

__global__ void rope_table_kernel(float2* __restrict__ cs) {
    int idx = blockIdx.x * 256 + threadIdx.x; // < 2048*32
    int t = idx >> 5, i = idx & 31;
    float inv_freq = powf(10000.0f, -(float)i / 32.0f);
    float a = (float)t * inv_freq;
    cs[idx] = make_float2(cosf(a), sinf(a));
}

// Vb[m][t][d] (2048x64) -> Vt[m][d][t] (64x2048), m = b*4+kvh
__global__ void transpose_v_kernel(const unsigned short* __restrict__ Vb,
                                   unsigned short* __restrict__ Vt) {
    __shared__ unsigned short tile[64][66];
    int t0 = blockIdx.x * 64, m = blockIdx.y;
    int tx = threadIdx.x, ty = threadIdx.y; // (32, 8)
    const unsigned short* src = Vb + (size_t)m * 2048 * 64;
    unsigned short* dst = Vt + (size_t)m * 64 * 2048;
#pragma unroll
    for (int i = 0; i < 8; i++) {
        int t = ty + i * 8;
        *(ushort2*)&tile[t][tx * 2] =
            *(const ushort2*)(src + (size_t)(t0 + t) * 64 + tx * 2);
    }
    __syncthreads();
#pragma unroll
    for (int i = 0; i < 8; i++) {
        int d = ty + i * 8;
        ushort2 o;
        o.x = tile[tx * 2][d];
        o.y = tile[tx * 2 + 1][d];
        *(ushort2*)(dst + (size_t)d * 2048 + t0 + tx * 2) = o;
    }
}

// ------------------------------------------------------------- QKV GEMM + RoPE
// C = Xb(4096x1024) @ W(1024x1536) with W supplied transposed (wt: 1536x1024).
// n in [0,1024): Q (RoPE + 0.125*log2e scale); [1024,1280): K (RoPE); [1280,1536): V.

__global__ __launch_bounds__(256) void gemm_qkv_kernel(
    const unsigned short* __restrict__ xb, const unsigned short* __restrict__ wt,
    const float2* __restrict__ cs, unsigned short* __restrict__ Qb,
    unsigned short* __restrict__ Kb, unsigned short* __restrict__ Vb) {
    __shared__ char smem[16384];
    char* As = smem;
    char* Bs = smem + 8192;
    const int tid = threadIdx.x;
    const int lane = tid & 63, w = tid >> 6;
    const int wm = w >> 1, wn = w & 1;
    const int m0 = blockIdx.y * 128, n0 = blockIdx.x * 128;
    const int l15 = lane & 15, g = lane >> 4;

    const int srow = tid >> 2;
    const int sc0 = (tid & 3) ^ swzf2(srow);
    const int sc1 = (tid & 3) ^ swzf2(srow + 64);
    const unsigned short* aRow0 = xb + (size_t)(m0 + srow) * 1024 + sc0 * 8;
    const unsigned short* aRow1 = xb + (size_t)(m0 + srow + 64) * 1024 + sc1 * 8;
    const unsigned short* bRow0 = wt + (size_t)(n0 + srow) * 1024 + sc0 * 8;
    const unsigned short* bRow1 = wt + (size_t)(n0 + srow + 64) * 1024 + sc1 * 8;

    f32x4 acc[4][4] = {};
    for (int kt = 0; kt < 32; kt++) {
        __syncthreads();
        GLDS16(aRow0 + kt * 32, As + tid * 16);
        GLDS16(aRow1 + kt * 32, As + tid * 16 + 4096);
        GLDS16(bRow0 + kt * 32, Bs + tid * 16);
        GLDS16(bRow1 + kt * 32, Bs + tid * 16 + 4096);
        __syncthreads();
        bshort8 af[4], bf[4];
#pragma unroll
        for (int fm = 0; fm < 4; fm++) {
            int row = wm * 64 + fm * 16 + l15;
            af[fm] = *(const bshort8*)(As + row * 64 + ((g ^ swzf2(row)) << 4));
        }
#pragma unroll
        for (int fn = 0; fn < 4; fn++) {
            int row = wn * 64 + fn * 16 + l15;
            bf[fn] = *(const bshort8*)(Bs + row * 64 + ((g ^ swzf2(row)) << 4));
        }
#pragma unroll
        for (int fm = 0; fm < 4; fm++)
#pragma unroll
            for (int fn = 0; fn < 4; fn++)
                acc[fm][fn] = __builtin_amdgcn_mfma_f32_16x16x32_bf16(
                    af[fm], bf[fn], acc[fm][fn], 0, 0, 0);
    }

    const bool isV = (n0 >= 1280);
    const bool isK = (n0 >= 1024) && !isV;
#pragma unroll
    for (int fm = 0; fm < 4; fm++) {
#pragma unroll
        for (int r = 0; r < 4; r++) {
            int m = m0 + wm * 64 + fm * 16 + g * 4 + r;
            int b = m >> 11, t = m & 2047;
            if (isV) {
#pragma unroll
                for (int fn = 0; fn < 4; fn++) {
                    int n = n0 + wn * 64 + fn * 16 + l15;
                    int d = n & 63, vh = (n - 1280) >> 6;
                    Vb[((size_t)(b * 4 + vh) * 2048 + t) * 64 + d] =
                        f2bf(acc[fm][fn][r]);
                }
            } else {
                float2 c0 = cs[t * 32 + l15];
                float2 c1 = cs[t * 32 + 16 + l15];
#pragma unroll
                for (int fn = 0; fn < 4; fn++) {
                    int n = n0 + wn * 64 + fn * 16 + l15;
                    int d = n & 63;
                    float val = acc[fm][fn][r];
                    float pair = acc[fm][fn ^ 2][r];
                    float rot = (fn < 2) ? -pair : pair;
                    float2 cc = (fn & 1) ? c1 : c0;
                    float o = val * cc.x + rot * cc.y;
                    if (isK) {
                        int kh = (n - 1024) >> 6;
                        Kb[((size_t)(b * 4 + kh) * 2048 + t) * 64 + d] = f2bf(o);
                    } else {
                        o *= 0.1803368801111504f;  // 0.125 * log2(e)
                        int h = n >> 6;
                        Qb[((size_t)(b * 16 + h) * 2048 + t) * 64 + d] = f2bf(o);
                    }
                }
            }
        }
    }
}

// ------------------------------------------------------------- flash attention
// Split-KV (flash-decoding): each block does <=8 KV tiles (512 kv) for one
// 64-row q-tile; writes unnormalized partial O (bf16) + m,l (f32).
// chunk id c in [0,80) per (b,h): qt<8 -> 1 chunk; 8-15 -> 2; 16-23 -> 3; 24-31 -> 4.

__global__ __launch_bounds__(256) void attn_kernel(
    const unsigned short* __restrict__ Qb, const unsigned short* __restrict__ Kb,
    const unsigned short* __restrict__ Vt, unsigned short* __restrict__ Opart,
    float* __restrict__ ml) {
    __shared__ char smem[40960];
    const int tid = threadIdx.x, lane = tid & 63, w = tid >> 6;
    const int l15 = lane & 15, g = lane >> 4;
    const int c = 79 - blockIdx.x;  // heavy chunks dispatched first
    const int h = blockIdx.y, b = blockIdx.z;
    int qt, s;
    if (c < 8)       { qt = c;                    s = 0; }
    else if (c < 24) { qt = 8 + ((c - 8) >> 1);   s = (c - 8) & 1; }
    else if (c < 48) { qt = 16 + (c - 24) / 3;    s = (c - 24) % 3; }
    else             { qt = 24 + ((c - 48) >> 2); s = (c - 48) & 3; }
    const int k0t = s * 8;                     // first KV tile (global index)
    const int nk = min(8, qt + 1 - k0t);       // tiles in this chunk
    const int qs = qt * 64;
    const int kvh = h >> 2;
    const int slot = (b * 16 + h) * 80 + c;

    const unsigned short* Kbase = Kb + (size_t)(b * 4 + kvh) * 2048 * 64;
    const unsigned short* Vbase = Vt + (size_t)(b * 4 + kvh) * 64 * 2048;
    const unsigned short* Qhead = Qb + (size_t)(b * 16 + h) * 2048 * 64;

    const int srow8 = lane >> 3;  // 0..7
    const int sci = lane & 7;     // chunk 0..7
    const int sk = (l15 & 7) ^ (l15 >> 3);  // row swizzle key
    const int strip = w * 2048;

    // ---- loop-invariant LDS addresses
    const int rowb = l15 * 128 + ((g ^ sk) << 4);
    const int Aq0 = strip + rowb;
    int Ak0 = 0x2000 + rowb;
    int Ak1 = Ak0 ^ 64;
    int Av0 = 0x6000 + rowb;
    int Av1 = Av0 ^ 64;
    const int pw0 = strip + l15 * 128 + (((2 * g) ^ sk) << 4);
    const int pw1 = strip + l15 * 128 + (((2 * g + 1) ^ sk) << 4);
    const int byteA0 = ((2 * g) & 3) * 32 + (g >> 1) * 8;
    const int byteB0 = ((2 * g + 1) & 3) * 32 + (g >> 1) * 8;
    const int prA0 = strip + l15 * 128 + (((byteA0 >> 4) ^ sk) << 4) + (byteA0 & 15);
    const int prB0 = strip + l15 * 128 + (((byteB0 >> 4) ^ sk) << 4) + (byteB0 & 15);

    // ---- staging geometry
    const int lc0 = sci ^ srow8;
    const int lc1 = sci ^ srow8 ^ 1;
    const int r0 = w * 16 + srow8, r1 = w * 16 + 8 + srow8;

    // prologue: stage Q + K tile k0t + V tile k0t
    GLDS16(Qhead + (size_t)(qs + r0) * 64 + lc0 * 8, smem + strip + lane * 16);
    GLDS16(Qhead + (size_t)(qs + r1) * 64 + lc1 * 8, smem + strip + lane * 16 + 1024);
    GLDS16(Kbase + (size_t)(k0t * 64 + r0) * 64 + lc0 * 8,
           smem + 0x2000 + strip + lane * 16);
    GLDS16(Kbase + (size_t)(k0t * 64 + r1) * 64 + lc1 * 8,
           smem + 0x2000 + strip + lane * 16 + 1024);
    GLDS16(Vbase + (size_t)r0 * 2048 + k0t * 64 + lc0 * 8,
           smem + 0x6000 + strip + lane * 16);
    GLDS16(Vbase + (size_t)r1 * 2048 + k0t * 64 + lc1 * 8,
           smem + 0x6000 + strip + lane * 16 + 1024);
    __syncthreads();

    bshort8 qf0 = *(const bshort8*)(smem + Aq0);
    bshort8 qf1 = *(const bshort8*)(smem + (Aq0 ^ 64));

    // prefetch pointers (tile k0t+1)
    const unsigned short* gk0 = Kbase + (size_t)((k0t + 1) * 64 + r0) * 64 + lc0 * 8;
    const unsigned short* gk1 = Kbase + (size_t)((k0t + 1) * 64 + r1) * 64 + lc1 * 8;
    const unsigned short* gv0 = Vbase + (size_t)r0 * 2048 + (k0t + 1) * 64 + lc0 * 8;
    const unsigned short* gv1 = Vbase + (size_t)r1 * 2048 + (k0t + 1) * 64 + lc1 * 8;
    int kdst = 0x4000 + strip + lane * 16;
    int vdst = 0x8000 + strip + lane * 16;

    float m_run = -1e30f, l_run = 0.f;
    f32x4 O[4] = {};
    const int qlocal = w * 16 + l15;

    for (int kt = 0; kt < nk; kt++) {
        if (kt < nk - 1) {
            GLDS16(gk0, smem + kdst);
            GLDS16(gk1, smem + kdst + 1024);
            GLDS16(gv0, smem + vdst);
            GLDS16(gv1, smem + vdst + 1024);
            gk0 += 4096; gk1 += 4096; gv0 += 64; gv1 += 64;
        }
        // S^T[kv][q] = mfma(K, Q): lane holds kv = 16fn+4g+r, q = l15
        f32x4 S[4];
#pragma unroll
        for (int fn = 0; fn < 4; fn++) {
            bshort8 k0 = *(const bshort8*)(smem + Ak0 + fn * 2048);
            bshort8 k1 = *(const bshort8*)(smem + Ak1 + fn * 2048);
            f32x4 a = {};
            a = __builtin_amdgcn_mfma_f32_16x16x32_bf16(k0, qf0, a, 0, 0, 0);
            a = __builtin_amdgcn_mfma_f32_16x16x32_bf16(k1, qf1, a, 0, 0, 0);
            S[fn] = a;
        }
        if (k0t + kt == qt) {  // causal mask on the diagonal tile
#pragma unroll
            for (int fn = 0; fn < 4; fn++)
#pragma unroll
                for (int r = 0; r < 4; r++)
                    if (fn * 16 + g * 4 + r > qlocal) S[fn][r] = -1e30f;
        }
        // online softmax (base-2), row q = l15 spread over 4 g-groups
        float mt = -1e30f;
#pragma unroll
        for (int fn = 0; fn < 4; fn++)
#pragma unroll
            for (int r = 0; r < 4; r++) mt = fmaxf(mt, S[fn][r]);
        mt = fmaxf(mt, __shfl_xor(mt, 16));
        mt = fmaxf(mt, __shfl_xor(mt, 32));
        float mn = fmaxf(m_run, mt);
        float alpha = exp2_fast(m_run - mn);
        m_run = mn;
        float p[4][4];
        float rs = 0.f;
#pragma unroll
        for (int fn = 0; fn < 4; fn++)
#pragma unroll
            for (int r = 0; r < 4; r++) {
                p[fn][r] = exp2_fast(S[fn][r] - mn);
                rs += p[fn][r];
            }
        rs += __shfl_xor(rs, 16);
        rs += __shfl_xor(rs, 32);
        l_run = l_run * alpha + rs;
#pragma unroll
        for (int fd = 0; fd < 4; fd++) O[fd] *= alpha;
        // P -> LDS: two b128 writes (kvpos layout, conflict-free)
        int4 w0v, w1v;
        w0v.x = cvt_pk_bf16(p[0][0], p[0][1]);
        w0v.y = cvt_pk_bf16(p[0][2], p[0][3]);
        w0v.z = cvt_pk_bf16(p[1][0], p[1][1]);
        w0v.w = cvt_pk_bf16(p[1][2], p[1][3]);
        w1v.x = cvt_pk_bf16(p[2][0], p[2][1]);
        w1v.y = cvt_pk_bf16(p[2][2], p[2][3]);
        w1v.z = cvt_pk_bf16(p[3][0], p[3][1]);
        w1v.w = cvt_pk_bf16(p[3][2], p[3][3]);
        *(int4*)(smem + pw0) = w0v;
        *(int4*)(smem + pw1) = w1v;
        asm volatile("s_waitcnt lgkmcnt(0)" ::: "memory");
        __builtin_amdgcn_sched_barrier(0);
        union PF { int2 d[2]; bshort8 v; };
        PF u0, u1;
        u0.d[0] = *(const int2*)(smem + prA0);
        u0.d[1] = *(const int2*)(smem + prB0);
        u1.d[0] = *(const int2*)(smem + (prA0 ^ 16));
        u1.d[1] = *(const int2*)(smem + (prB0 ^ 16));
        // O^T[d][q] += mfma(V^T, P)
#pragma unroll
        for (int fd = 0; fd < 4; fd++) {
            bshort8 v0 = *(const bshort8*)(smem + Av0 + fd * 2048);
            bshort8 v1 = *(const bshort8*)(smem + Av1 + fd * 2048);
            O[fd] = __builtin_amdgcn_mfma_f32_16x16x32_bf16(v0, u0.v, O[fd], 0, 0, 0);
            O[fd] = __builtin_amdgcn_mfma_f32_16x16x32_bf16(v1, u1.v, O[fd], 0, 0, 0);
        }
        Ak0 ^= 0x6000; Ak1 ^= 0x6000; Av0 ^= 0xE000; Av1 ^= 0xE000;
        kdst ^= 0x6000; vdst ^= 0xE000;
        if (kt < nk - 1) __syncthreads();
    }

    // epilogue: write m,l and UNNORMALIZED O partial (transpose via LDS strip)
    if (g == 0) {
        ((float2*)ml)[(size_t)slot * 64 + w * 16 + l15] =
            make_float2(m_run, l_run);
    }
#pragma unroll
    for (int fd = 0; fd < 4; fd++)
#pragma unroll
        for (int w2 = 0; w2 < 2; w2++) {
            unsigned word = cvt_pk_bf16(O[fd][2 * w2], O[fd][2 * w2 + 1]);
            int byte = fd * 32 + g * 8 + w2 * 4;
            *(unsigned*)(smem + strip + l15 * 128 + (((byte >> 4) ^ sk) << 4) +
                         (byte & 15)) = word;
        }
    asm volatile("s_waitcnt lgkmcnt(0)" ::: "memory");
    __builtin_amdgcn_sched_barrier(0);
#pragma unroll
    for (int it = 0; it < 2; it++) {
        int r16 = it * 8 + srow8;
        int4 vv = *(const int4*)(smem + strip + r16 * 128 +
                                 ((sci ^ srow8 ^ it) << 4));
        *(int4*)(Opart + (size_t)slot * 4096 + (w * 16 + r16) * 64 + sci * 8) = vv;
    }
}

// ------------------------------------------------------------- split combine
// Per (qt,h,b): merge up to 4 partials -> normalized Ob[b*2048+t][h*64+d] bf16.
__global__ __launch_bounds__(256) void combine_kernel(
    const unsigned short* __restrict__ Opart, const float* __restrict__ ml,
    unsigned short* __restrict__ Ob) {
    const int qt = blockIdx.x, h = blockIdx.y, b = blockIdx.z;
    const int S = (qt >> 3) + 1;
    int c0;
    if (qt < 8)       c0 = qt;
    else if (qt < 16) c0 = 8 + (qt - 8) * 2;
    else if (qt < 24) c0 = 24 + (qt - 16) * 3;
    else              c0 = 48 + (qt - 24) * 4;
    const int slotbase = (b * 16 + h) * 80 + c0;
    const int t = threadIdx.x;
    const int q = t >> 2, dq = (t & 3) * 16;
    const float2* ml2 = (const float2*)ml;

    float m[4], l[4];
    float mstar = -1e30f;
#pragma unroll
    for (int i = 0; i < 4; i++) {
        m[i] = -1e30f; l[i] = 0.f;
        if (i < S) {
            float2 v = ml2[(size_t)(slotbase + i) * 64 + q];
            m[i] = v.x; l[i] = v.y;
            mstar = fmaxf(mstar, v.x);
        }
    }
    float L = 0.f;
    float wgt[4];
#pragma unroll
    for (int i = 0; i < 4; i++) {
        wgt[i] = (i < S) ? exp2f(m[i] - mstar) : 0.f;
        L += wgt[i] * l[i];
    }
    float acc[16] = {};
#pragma unroll
    for (int i = 0; i < 4; i++) {
        if (i < S) {
            const unsigned short* P =
                Opart + (size_t)(slotbase + i) * 4096 + q * 64 + dq;
            int4 a0 = *(const int4*)P;
            int4 a1 = *(const int4*)(P + 8);
            unsigned u[8] = {(unsigned)a0.x, (unsigned)a0.y, (unsigned)a0.z,
                             (unsigned)a0.w, (unsigned)a1.x, (unsigned)a1.y,
                             (unsigned)a1.z, (unsigned)a1.w};
            float wi = wgt[i];
#pragma unroll
            for (int j = 0; j < 8; j++) {
                acc[2 * j]     += wi * bf2f((unsigned short)(u[j] & 0xFFFF));
                acc[2 * j + 1] += wi * bf2f((unsigned short)(u[j] >> 16));
            }
        }
    }
    float invL = 1.0f / L;
    int4 o0, o1;
    o0.x = cvt_pk_bf16(acc[0] * invL, acc[1] * invL);
    o0.y = cvt_pk_bf16(acc[2] * invL, acc[3] * invL);
    o0.z = cvt_pk_bf16(acc[4] * invL, acc[5] * invL);
    o0.w = cvt_pk_bf16(acc[6] * invL, acc[7] * invL);
    o1.x = cvt_pk_bf16(acc[8] * invL, acc[9] * invL);
    o1.y = cvt_pk_bf16(acc[10] * invL, acc[11] * invL);
    o1.z = cvt_pk_bf16(acc[12] * invL, acc[13] * invL);
    o1.w = cvt_pk_bf16(acc[14] * invL, acc[15] * invL);
    unsigned short* dst =
        Ob + (size_t)(b * 2048 + qt * 64 + q) * 1024 + h * 64 + dq;
    *(int4*)dst = o0;
    *(int4*)(dst + 8) = o1;
}

// ------------------------------------------------------------- output GEMM
__global__ __launch_bounds__(256) void gemm_out_kernel(
    const unsigned short* __restrict__ ab, const unsigned short* __restrict__ wot,
    float* __restrict__ out) {
    __shared__ char smem[16384];
    char* As = smem;
    char* Bs = smem + 8192;
    const int tid = threadIdx.x;
    const int lane = tid & 63, w = tid >> 6;
    const int wm = w >> 1, wn = w & 1;
    const int m0 = blockIdx.y * 128, n0 = blockIdx.x * 128;
    const int l15 = lane & 15, g = lane >> 4;

    const int srow = tid >> 2;
    const int sc0 = (tid & 3) ^ swzf2(srow);
    const int sc1 = (tid & 3) ^ swzf2(srow + 64);
    const unsigned short* aRow0 = ab + (size_t)(m0 + srow) * 1024 + sc0 * 8;
    const unsigned short* aRow1 = ab + (size_t)(m0 + srow + 64) * 1024 + sc1 * 8;
    const unsigned short* bRow0 = wot + (size_t)(n0 + srow) * 1024 + sc0 * 8;
    const unsigned short* bRow1 = wot + (size_t)(n0 + srow + 64) * 1024 + sc1 * 8;

    f32x4 acc[4][4] = {};
    for (int kt = 0; kt < 32; kt++) {
        __syncthreads();
        GLDS16(aRow0 + kt * 32, As + tid * 16);
        GLDS16(aRow1 + kt * 32, As + tid * 16 + 4096);
        GLDS16(bRow0 + kt * 32, Bs + tid * 16);
        GLDS16(bRow1 + kt * 32, Bs + tid * 16 + 4096);
        __syncthreads();
        bshort8 af[4], bf[4];
#pragma unroll
        for (int fm = 0; fm < 4; fm++) {
            int row = wm * 64 + fm * 16 + l15;
            af[fm] = *(const bshort8*)(As + row * 64 + ((g ^ swzf2(row)) << 4));
        }
#pragma unroll
        for (int fn = 0; fn < 4; fn++) {
            int row = wn * 64 + fn * 16 + l15;
            bf[fn] = *(const bshort8*)(Bs + row * 64 + ((g ^ swzf2(row)) << 4));
        }
#pragma unroll
        for (int fm = 0; fm < 4; fm++)
#pragma unroll
            for (int fn = 0; fn < 4; fn++)
                acc[fm][fn] = __builtin_amdgcn_mfma_f32_16x16x32_bf16(
                    af[fm], bf[fn], acc[fm][fn], 0, 0, 0);
    }
#pragma unroll
    for (int fm = 0; fm < 4; fm++)
#pragma unroll
        for (int r = 0; r < 4; r++) {
            int m = m0 + wm * 64 + fm * 16 + g * 4 + r;
#pragma unroll
            for (int fn = 0; fn < 4; fn++) {
                int n = n0 + wn * 64 + fn * 16 + l15;
                out[(size_t)m * 1024 + n] = acc[fm][fn][r];
            }
        }
}

// ---------------------------------------------------------------- launch

extern "C" void kernel_launch(void* const* d_in, const int* in_sizes, int n_in,
                              void* d_out, int out_size, void* d_ws, size_t ws_size,
                              hipStream_t stream) {
    const float* x = (const float*)d_in[0];
    const float* wq = (const float*)d_in[1];
    const float* wk = (const float*)d_in[2];
    const float* wv = (const float*)d_in[3];
    const float* wo = (const float*)d_in[4];
    float* out = (float*)d_out;
    char* ws = (char*)d_ws;

    unsigned short* xb = (unsigned short*)(ws);                  // 8 MB (later Ob)
    unsigned short* wt = (unsigned short*)(ws + 8388608);        // 3 MB (later ml)
    float* ml = (float*)(ws + 8388608);                          // 1.31 MB
    unsigned short* wot = (unsigned short*)(ws + 11534336);      // 2 MB
    float2* cs = (float2*)(ws + 13631488);                       // 0.5 MB
    unsigned short* Qb = (unsigned short*)(ws + 14155776);       // 8 MB
    unsigned short* Kb = (unsigned short*)(ws + 22544384);       // 2 MB
    unsigned short* Vb = (unsigned short*)(ws + 24641536);       // 2 MB
    unsigned short* Vtr = (unsigned short*)(ws + 26738688);      // 2 MB
    unsigned short* Opart = (unsigned short*)(ws + 28835840);    // 21 MB
    unsigned short* Ob = xb;                                     // reuse xb region

    hipLaunchKernelGGL(cast_x_kernel, dim3(2048), dim3(256), 0, stream, x, xb,
                       4194304 / 4);
    hipLaunchKernelGGL(transpose_cast_kernel, dim3(32, 32), dim3(32, 8), 0, stream,
                       wq, wt, 1024, 1024);
    hipLaunchKernelGGL(transpose_cast_kernel, dim3(8, 32), dim3(32, 8), 0, stream,
                       wk, wt + 1024 * 1024, 1024, 256);
    hipLaunchKernelGGL(transpose_cast_kernel, dim3(8, 32), dim3(32, 8), 0, stream,
                       wv, wt + 1280 * 1024, 1024, 256);
    hipLaunchKernelGGL(transpose_cast_kernel, dim3(32, 32), dim3(32, 8), 0, stream,
                       wo, wot, 1024, 1024);
    hipLaunchKernelGGL(rope_table_kernel, dim3(256), dim3(256), 0, stream, cs);
    hipLaunchKernelGGL(gemm_qkv_kernel, dim3(12, 32), dim3(256), 0, stream, xb, wt,
                       cs, Qb, Kb, Vb);
    hipLaunchKernelGGL(transpose_v_kernel, dim3(32, 8), dim3(32, 8), 0, stream, Vb,
                       Vtr);
    hipLaunchKernelGGL(attn_kernel, dim3(80, 16, 2), dim3(256), 0, stream, Qb, Kb,
                       Vtr, Opart, ml);
    hipLaunchKernelGGL(combine_kernel, dim3(32, 16, 2), dim3(256), 0, stream,
                       Opart, ml, Ob);
    hipLaunchKernelGGL(gemm_out_kernel, dim3(8, 32), dim3(256), 0, stream, Ob, wot,
                       out);
}

// Round 5
// 128.892 us; speedup vs baseline: 1.1695x; 1.0626x over previous
//
#include <hip/hip_runtime.h>

typedef short bshort8 __attribute__((ext_vector_type(8)));
typedef float f32x4 __attribute__((ext_vector_type(4)));

#define DEVFN static __device__ __forceinline__

DEVFN unsigned short f2bf(float f) {
    union { float f; unsigned u; } v; v.f = f;
    unsigned r = (v.u + 0x7FFFu + ((v.u >> 16) & 1u)) >> 16;
    return (unsigned short)r;
}

DEVFN float bf2f(unsigned short u) {
    union { unsigned u; float f; } v; v.u = (unsigned)u << 16;
    return v.f;
}

DEVFN unsigned cvt_pk_bf16(float a, float b) {
    unsigned r;
    asm("v_cvt_pk_bf16_f32 %0, %1, %2" : "=v"(r) : "v"(a), "v"(b));
    return r;
}

DEVFN float exp2_fast(float x) {
    float r;
    asm("v_exp_f32 %0, %1" : "=v"(r) : "v"(x));
    return r;
}

DEVFN float max3f(float a, float b, float c) {
    float r;
    asm("v_max3_f32 %0, %1, %2, %3" : "=v"(r) : "v"(a), "v"(b), "v"(c));
    return r;
}

// XOR swizzle for 64-byte LDS rows (4 chunks of 16B)
DEVFN int swzf2(int row) { return (row & 3) ^ ((row >> 2) & 3); }

#define GLDS16(g, l)                                                            \
    __builtin_amdgcn_global_load_lds(                                           \
        (__attribute__((address_space(1))) void*)(g),                           \
        (__attribute__((address_space(3))) void*)(l), 16, 0, 0)

// ---------------------------------------------------------------- prep kernels

__global__ void cast_x_kernel(const float* __restrict__ x,
                              unsigned short* __restrict__ xb, int n4) {
    int i = blockIdx.x * blockDim.x + threadIdx.x;
    int stride = gridDim.x * blockDim.x;
    for (; i < n4; i += stride) {
        float4 v = ((const float4*)x)[i];
        ushort4 o;
        o.x = f2bf(v.x); o.y = f2bf(v.y); o.z = f2bf(v.z); o.w = f2bf(v.w);
        ((ushort4*)xb)[i] = o;
    }
}

// All 4 weight transposes in one launch. src K x N f32 -> dst N x K bf16.
__global__ void transpose_all_kernel(const float* __restrict__ wq,
                                     const float* __restrict__ wk,
                                     const float* __restrict__ wv,
                                     const float* __restrict__ wo,
                                     unsigned short* __restrict__ wt,
                                     unsigned short* __restrict__ wot) {
    const int z = blockIdx.z;
    const float* src;
    unsigned short* dst;
    int N;
    if (z == 0)      { src = wq; dst = wt;                N = 1024; }
    else if (z == 1) { src = wk; dst = wt + 1024 * 1024;  N = 256; }
    else if (z == 2) { src = wv; dst = wt + 1280 * 1024;  N = 256; }
    else             { src = wo; dst = wot;               N = 1024; }
    if (blockIdx.x * 32 >= N) return;
    __shared__ float tile[32][33];
    int n0 = blockIdx.x * 32, k0 = blockIdx.y * 32;
    int tx = threadIdx.x, ty = threadIdx.y;  // (32, 8)
#pragma unroll
    for (int i = 0; i < 4; i++)
        tile[ty + i * 8][tx] = src[(size_t)(k0 + ty + i * 8) * N + n0 + tx];
    __syncthreads();
#pragma unroll
    for (int i = 0; i < 4; i++)
        dst[(size_t)(n0 + ty + i * 8) * 1024 + k0 + tx] = f2bf(tile[tx][ty + i * 8]);
}

__global__ void rope_table_kernel(float2* __restrict__ cs) {
    int idx = blockIdx.x * 256 + threadIdx.x;  // < 2048*32
    int t = idx >> 5, i = idx & 31;
    float inv_freq = powf(10000.0f, -(float)i / 32.0f);
    float a = (float)t * inv_freq;
    cs[idx] = make_float2(cosf(a), sinf(a));
}

// Vb[m][t][d] (2048x64) -> Vt[m][d][t] (64x2048), m = b*4+kvh
__global__ void transpose_v_kernel(const unsigned short* __restrict__ Vb,
                                   unsigned short* __restrict__ Vt) {
    __shared__ unsigned short tile[64][66];
    int t0 = blockIdx.x * 64, m = blockIdx.y;
    int tx = threadIdx.x, ty = threadIdx.y;  // (32, 8)
    const unsigned short* src = Vb + (size_t)m * 2048 * 64;
    unsigned short* dst = Vt + (size_t)m * 64 * 2048;
#pragma unroll
    for (int i = 0; i < 8; i++) {
        int t = ty + i * 8;
        *(ushort2*)&tile[t][tx * 2] =
            *(const ushort2*)(src + (size_t)(t0 + t) * 64 + tx * 2);
    }
    __syncthreads();
#pragma unroll
    for (int i = 0; i < 8; i++) {
        int d = ty + i * 8;
        ushort2 o;
        o.x = tile[tx * 2][d];
        o.y = tile[tx * 2 + 1][d];
        *(ushort2*)(dst + (size_t)d * 2048 + t0 + tx * 2) = o;
    }
}

// ------------------------------------------------------------- QKV GEMM + RoPE
// 2-phase pipelined: stage next K-tile before computing current.
// LDS: A bufs at 0x0000/0x2000 (8KB each), B bufs at 0x4000/0x6000.

__global__ __launch_bounds__(256) void gemm_qkv_kernel(
    const unsigned short* __restrict__ xb, const unsigned short* __restrict__ wt,
    const float2* __restrict__ cs, unsigned short* __restrict__ Qb,
    unsigned short* __restrict__ Kb, unsigned short* __restrict__ Vb) {
    __shared__ char smem[32768];
    const int tid = threadIdx.x;
    const int lane = tid & 63, w = tid >> 6;
    const int wm = w >> 1, wn = w & 1;
    const int m0 = blockIdx.y * 128, n0 = blockIdx.x * 128;
    const int l15 = lane & 15, g = lane >> 4;

    const int srow = tid >> 2;
    const int sc0 = (tid & 3) ^ swzf2(srow);
    const int sc1 = (tid & 3) ^ swzf2(srow + 64);
    const unsigned short* aRow0 = xb + (size_t)(m0 + srow) * 1024 + sc0 * 8;
    const unsigned short* aRow1 = xb + (size_t)(m0 + srow + 64) * 1024 + sc1 * 8;
    const unsigned short* bRow0 = wt + (size_t)(n0 + srow) * 1024 + sc0 * 8;
    const unsigned short* bRow1 = wt + (size_t)(n0 + srow + 64) * 1024 + sc1 * 8;

    int aOff[4], bOff[4];
#pragma unroll
    for (int fm = 0; fm < 4; fm++) {
        int row = wm * 64 + fm * 16 + l15;
        aOff[fm] = row * 64 + ((g ^ swzf2(row)) << 4);
    }
#pragma unroll
    for (int fn = 0; fn < 4; fn++) {
        int row = wn * 64 + fn * 16 + l15;
        bOff[fn] = 0x4000 + row * 64 + ((g ^ swzf2(row)) << 4);
    }

    f32x4 acc[4][4] = {};
    // prologue: stage kt=0 into buffer 0
    GLDS16(aRow0, smem + tid * 16);
    GLDS16(aRow1, smem + tid * 16 + 4096);
    GLDS16(bRow0, smem + 0x4000 + tid * 16);
    GLDS16(bRow1, smem + 0x4000 + tid * 16 + 4096);
    asm volatile("s_waitcnt vmcnt(0)" ::: "memory");
    __builtin_amdgcn_s_barrier();

    for (int kt = 0; kt < 32; kt++) {
        const int cur = (kt & 1) << 13;  // 0 or 0x2000
        if (kt < 31) {
            const int nxt = cur ^ 0x2000;
            GLDS16(aRow0 + (kt + 1) * 32, smem + nxt + tid * 16);
            GLDS16(aRow1 + (kt + 1) * 32, smem + nxt + tid * 16 + 4096);
            GLDS16(bRow0 + (kt + 1) * 32, smem + 0x4000 + nxt + tid * 16);
            GLDS16(bRow1 + (kt + 1) * 32, smem + 0x4000 + nxt + tid * 16 + 4096);
        }
        bshort8 af[4], bf[4];
#pragma unroll
        for (int fm = 0; fm < 4; fm++)
            af[fm] = *(const bshort8*)(smem + cur + aOff[fm]);
#pragma unroll
        for (int fn = 0; fn < 4; fn++)
            bf[fn] = *(const bshort8*)(smem + cur + bOff[fn]);
        asm volatile("s_waitcnt lgkmcnt(0)" ::: "memory");
        __builtin_amdgcn_sched_barrier(0);
#pragma unroll
        for (int fm = 0; fm < 4; fm++)
#pragma unroll
            for (int fn = 0; fn < 4; fn++)
                acc[fm][fn] = __builtin_amdgcn_mfma_f32_16x16x32_bf16(
                    af[fm], bf[fn], acc[fm][fn], 0, 0, 0);
        if (kt < 31) {
            asm volatile("s_waitcnt vmcnt(0)" ::: "memory");
            __builtin_amdgcn_s_barrier();
        }
    }

    const bool isV = (n0 >= 1280);
    const bool isK = (n0 >= 1024) && !isV;
#pragma unroll
    for (int fm = 0; fm < 4; fm++) {
#pragma unroll
        for (int r = 0; r < 4; r++) {
            int m = m0 + wm * 64 + fm * 16 + g * 4 + r;
            int b = m >> 11, t = m & 2047;
            if (isV) {
#pragma unroll
                for (int fn = 0; fn < 4; fn++) {
                    int n = n0 + wn * 64 + fn * 16 + l15;
                    int d = n & 63, vh = (n - 1280) >> 6;
                    Vb[((size_t)(b * 4 + vh) * 2048 + t) * 64 + d] =
                        f2bf(acc[fm][fn][r]);
                }
            } else {
                float2 c0 = cs[t * 32 + l15];
                float2 c1 = cs[t * 32 + 16 + l15];
#pragma unroll
                for (int fn = 0; fn < 4; fn++) {
                    int n = n0 + wn * 64 + fn * 16 + l15;
                    int d = n & 63;
                    float val = acc[fm][fn][r];
                    float pair = acc[fm][fn ^ 2][r];
                    float rot = (fn < 2) ? -pair : pair;
                    float2 cc = (fn & 1) ? c1 : c0;
                    float o = val * cc.x + rot * cc.y;
                    if (isK) {
                        int kh = (n - 1024) >> 6;
                        Kb[((size_t)(b * 4 + kh) * 2048 + t) * 64 + d] = f2bf(o);
                    } else {
                        o *= 0.1803368801111504f;  // 0.125 * log2(e)
                        int h = n >> 6;
                        Qb[((size_t)(b * 16 + h) * 2048 + t) * 64 + d] = f2bf(o);
                    }
                }
            }
        }
    }
}

// ------------------------------------------------------------- flash attention
// Split-KV (flash-decoding): each block does <=8 KV tiles (512 kv) for one
// 64-row q-tile; writes unnormalized partial O (bf16) + m,l (f32).
// chunk id c in [0,80) per (b,h): qt<8 -> 1 chunk; 8-15 -> 2; 16-23 -> 3; 24-31 -> 4.
// Softmax base-2 with defer-rescale (THR=8); l via ones-MFMA row-sum of P.

__global__ __launch_bounds__(256) void attn_kernel(
    const unsigned short* __restrict__ Qb, const unsigned short* __restrict__ Kb,
    const unsigned short* __restrict__ Vt, unsigned short* __restrict__ Opart,
    float* __restrict__ ml) {
    __shared__ char smem[40960];
    const int tid = threadIdx.x, lane = tid & 63, w = tid >> 6;
    const int l15 = lane & 15, g = lane >> 4;
    const int c = 79 - blockIdx.x;  // heavy chunks dispatched first
    const int h = blockIdx.y, b = blockIdx.z;
    int qt, s;
    if (c < 8)       { qt = c;                    s = 0; }
    else if (c < 24) { qt = 8 + ((c - 8) >> 1);   s = (c - 8) & 1; }
    else if (c < 48) { qt = 16 + (c - 24) / 3;    s = (c - 24) % 3; }
    else             { qt = 24 + ((c - 48) >> 2); s = (c - 48) & 3; }
    const int k0t = s * 8;                // first KV tile (global index)
    const int nk = min(8, qt + 1 - k0t);  // tiles in this chunk
    const int qs = qt * 64;
    const int kvh = h >> 2;
    const int slot = (b * 16 + h) * 80 + c;

    const unsigned short* Kbase = Kb + (size_t)(b * 4 + kvh) * 2048 * 64;
    const unsigned short* Vbase = Vt + (size_t)(b * 4 + kvh) * 64 * 2048;
    const unsigned short* Qhead = Qb + (size_t)(b * 16 + h) * 2048 * 64;

    const int srow8 = lane >> 3;  // 0..7
    const int sci = lane & 7;     // chunk 0..7
    const int sk = (l15 & 7) ^ (l15 >> 3);  // row swizzle key
    const int strip = w * 2048;

    // ---- loop-invariant LDS addresses
    const int rowb = l15 * 128 + ((g ^ sk) << 4);
    const int Aq0 = strip + rowb;
    int Ak0 = 0x2000 + rowb;
    int Ak1 = Ak0 ^ 64;
    int Av0 = 0x6000 + rowb;
    int Av1 = Av0 ^ 64;
    const int pw0 = strip + l15 * 128 + (((2 * g) ^ sk) << 4);
    const int pw1 = strip + l15 * 128 + (((2 * g + 1) ^ sk) << 4);
    const int byteA0 = ((2 * g) & 3) * 32 + (g >> 1) * 8;
    const int byteB0 = ((2 * g + 1) & 3) * 32 + (g >> 1) * 8;
    const int prA0 = strip + l15 * 128 + (((byteA0 >> 4) ^ sk) << 4) + (byteA0 & 15);
    const int prB0 = strip + l15 * 128 + (((byteB0 >> 4) ^ sk) << 4) + (byteB0 & 15);

    // ---- staging geometry
    const int lc0 = sci ^ srow8;
    const int lc1 = sci ^ srow8 ^ 1;
    const int r0 = w * 16 + srow8, r1 = w * 16 + 8 + srow8;

    // prologue: stage Q + K tile k0t + V tile k0t
    GLDS16(Qhead + (size_t)(qs + r0) * 64 + lc0 * 8, smem + strip + lane * 16);
    GLDS16(Qhead + (size_t)(qs + r1) * 64 + lc1 * 8, smem + strip + lane * 16 + 1024);
    GLDS16(Kbase + (size_t)(k0t * 64 + r0) * 64 + lc0 * 8,
           smem + 0x2000 + strip + lane * 16);
    GLDS16(Kbase + (size_t)(k0t * 64 + r1) * 64 + lc1 * 8,
           smem + 0x2000 + strip + lane * 16 + 1024);
    GLDS16(Vbase + (size_t)r0 * 2048 + k0t * 64 + lc0 * 8,
           smem + 0x6000 + strip + lane * 16);
    GLDS16(Vbase + (size_t)r1 * 2048 + k0t * 64 + lc1 * 8,
           smem + 0x6000 + strip + lane * 16 + 1024);
    __syncthreads();

    bshort8 qf0 = *(const bshort8*)(smem + Aq0);
    bshort8 qf1 = *(const bshort8*)(smem + (Aq0 ^ 64));
    bshort8 ones;
#pragma unroll
    for (int j = 0; j < 8; j++) ones[j] = (short)0x3F80;  // bf16 1.0

    // prefetch pointers (tile k0t+1)
    const unsigned short* gk0 = Kbase + (size_t)((k0t + 1) * 64 + r0) * 64 + lc0 * 8;
    const unsigned short* gk1 = Kbase + (size_t)((k0t + 1) * 64 + r1) * 64 + lc1 * 8;
    const unsigned short* gv0 = Vbase + (size_t)r0 * 2048 + (k0t + 1) * 64 + lc0 * 8;
    const unsigned short* gv1 = Vbase + (size_t)r1 * 2048 + (k0t + 1) * 64 + lc1 * 8;
    int kdst = 0x4000 + strip + lane * 16;
    int vdst = 0x8000 + strip + lane * 16;

    float m_run = -1e30f;
    f32x4 l_acc = {};
    f32x4 O[4] = {};
    const int qlocal = w * 16 + l15;

    for (int kt = 0; kt < nk; kt++) {
        if (kt < nk - 1) {
            GLDS16(gk0, smem + kdst);
            GLDS16(gk1, smem + kdst + 1024);
            GLDS16(gv0, smem + vdst);
            GLDS16(gv1, smem + vdst + 1024);
            gk0 += 4096; gk1 += 4096; gv0 += 64; gv1 += 64;
        }
        // S^T[kv][q] = mfma(K, Q): lane holds kv = 16fn+4g+r, q = l15
        f32x4 S[4];
        __builtin_amdgcn_s_setprio(1);
#pragma unroll
        for (int fn = 0; fn < 4; fn++) {
            bshort8 k0 = *(const bshort8*)(smem + Ak0 + fn * 2048);
            bshort8 k1 = *(const bshort8*)(smem + Ak1 + fn * 2048);
            f32x4 a = {};
            a = __builtin_amdgcn_mfma_f32_16x16x32_bf16(k0, qf0, a, 0, 0, 0);
            a = __builtin_amdgcn_mfma_f32_16x16x32_bf16(k1, qf1, a, 0, 0, 0);
            S[fn] = a;
        }
        __builtin_amdgcn_s_setprio(0);
        if (k0t + kt == qt) {  // causal mask on the diagonal tile
#pragma unroll
            for (int fn = 0; fn < 4; fn++)
#pragma unroll
                for (int r = 0; r < 4; r++)
                    if (fn * 16 + g * 4 + r > qlocal) S[fn][r] = -1e30f;
        }
        // tile max via v_max3 tree, then cross-group reduce
        float ta = max3f(S[0][0], S[0][1], S[0][2]);
        float tb = max3f(S[0][3], S[1][0], S[1][1]);
        float tc = max3f(S[1][2], S[1][3], S[2][0]);
        float td = max3f(S[2][1], S[2][2], S[2][3]);
        float te = max3f(S[3][0], S[3][1], S[3][2]);
        float mt = fmaxf(max3f(ta, tb, tc), max3f(td, te, S[3][3]));
        mt = fmaxf(mt, __shfl_xor(mt, 16));
        mt = fmaxf(mt, __shfl_xor(mt, 32));
        // defer-rescale: only rescale when max grew by > 8 (base-2 units)
        if (!__all(mt <= m_run + 8.0f)) {
            float mn = fmaxf(m_run, mt);
            float alpha = exp2_fast(m_run - mn);
            m_run = mn;
            l_acc *= alpha;
#pragma unroll
            for (int fd = 0; fd < 4; fd++) O[fd] *= alpha;
        }
        float p[4][4];
#pragma unroll
        for (int fn = 0; fn < 4; fn++)
#pragma unroll
            for (int r = 0; r < 4; r++) p[fn][r] = exp2_fast(S[fn][r] - m_run);
        // P -> LDS: two b128 writes (kvpos layout, conflict-free)
        int4 w0v, w1v;
        w0v.x = cvt_pk_bf16(p[0][0], p[0][1]);
        w0v.y = cvt_pk_bf16(p[0][2], p[0][3]);
        w0v.z = cvt_pk_bf16(p[1][0], p[1][1]);
        w0v.w = cvt_pk_bf16(p[1][2], p[1][3]);
        w1v.x = cvt_pk_bf16(p[2][0], p[2][1]);
        w1v.y = cvt_pk_bf16(p[2][2], p[2][3]);
        w1v.z = cvt_pk_bf16(p[3][0], p[3][1]);
        w1v.w = cvt_pk_bf16(p[3][2], p[3][3]);
        *(int4*)(smem + pw0) = w0v;
        *(int4*)(smem + pw1) = w1v;
        asm volatile("s_waitcnt lgkmcnt(0)" ::: "memory");
        __builtin_amdgcn_sched_barrier(0);
        union PF { int2 d[2]; bshort8 v; };
        PF u0, u1;
        u0.d[0] = *(const int2*)(smem + prA0);
        u0.d[1] = *(const int2*)(smem + prB0);
        u1.d[0] = *(const int2*)(smem + (prA0 ^ 16));
        u1.d[1] = *(const int2*)(smem + (prB0 ^ 16));
        // l row-sum via ones-MFMA (sums all 64 kv of bf16 P, matches PV numerics)
        __builtin_amdgcn_s_setprio(1);
        l_acc = __builtin_amdgcn_mfma_f32_16x16x32_bf16(ones, u0.v, l_acc, 0, 0, 0);
        l_acc = __builtin_amdgcn_mfma_f32_16x16x32_bf16(ones, u1.v, l_acc, 0, 0, 0);
        // O^T[d][q] += mfma(V^T, P)
#pragma unroll
        for (int fd = 0; fd < 4; fd++) {
            bshort8 v0 = *(const bshort8*)(smem + Av0 + fd * 2048);
            bshort8 v1 = *(const bshort8*)(smem + Av1 + fd * 2048);
            O[fd] = __builtin_amdgcn_mfma_f32_16x16x32_bf16(v0, u0.v, O[fd], 0, 0, 0);
            O[fd] = __builtin_amdgcn_mfma_f32_16x16x32_bf16(v1, u1.v, O[fd], 0, 0, 0);
        }
        __builtin_amdgcn_s_setprio(0);
        Ak0 ^= 0x6000; Ak1 ^= 0x6000; Av0 ^= 0xE000; Av1 ^= 0xE000;
        kdst ^= 0x6000; vdst ^= 0xE000;
        if (kt < nk - 1) __syncthreads();
    }

    // epilogue: write m,l and UNNORMALIZED O partial (transpose via LDS strip)
    if (g == 0) {
        ((float2*)ml)[(size_t)slot * 64 + w * 16 + l15] =
            make_float2(m_run, l_acc[0]);
    }
#pragma unroll
    for (int fd = 0; fd < 4; fd++)
#pragma unroll
        for (int w2 = 0; w2 < 2; w2++) {
            unsigned word = cvt_pk_bf16(O[fd][2 * w2], O[fd][2 * w2 + 1]);
            int byte = fd * 32 + g * 8 + w2 * 4;
            *(unsigned*)(smem + strip + l15 * 128 + (((byte >> 4) ^ sk) << 4) +
                         (byte & 15)) = word;
        }
    asm volatile("s_waitcnt lgkmcnt(0)" ::: "memory");
    __builtin_amdgcn_sched_barrier(0);
#pragma unroll
    for (int it = 0; it < 2; it++) {
        int r16 = it * 8 + srow8;
        int4 vv = *(const int4*)(smem + strip + r16 * 128 +
                                 ((sci ^ srow8 ^ it) << 4));
        *(int4*)(Opart + (size_t)slot * 4096 + (w * 16 + r16) * 64 + sci * 8) = vv;
    }
}

// ------------------------------------------------------------- split combine
// Per (qt,h,b): merge up to 4 partials -> normalized Ob[b*2048+t][h*64+d] bf16.
__global__ __launch_bounds__(256) void combine_kernel(
    const unsigned short* __restrict__ Opart, const float* __restrict__ ml,
    unsigned short* __restrict__ Ob) {
    const int qt = blockIdx.x, h = blockIdx.y, b = blockIdx.z;
    const int S = (qt >> 3) + 1;
    int c0;
    if (qt < 8)       c0 = qt;
    else if (qt < 16) c0 = 8 + (qt - 8) * 2;
    else if (qt < 24) c0 = 24 + (qt - 16) * 3;
    else              c0 = 48 + (qt - 24) * 4;
    const int slotbase = (b * 16 + h) * 80 + c0;
    const int t = threadIdx.x;
    const int q = t >> 2, dq = (t & 3) * 16;
    const float2* ml2 = (const float2*)ml;

    float m[4], l[4];
    float mstar = -1e30f;
#pragma unroll
    for (int i = 0; i < 4; i++) {
        m[i] = -1e30f; l[i] = 0.f;
        if (i < S) {
            float2 v = ml2[(size_t)(slotbase + i) * 64 + q];
            m[i] = v.x; l[i] = v.y;
            mstar = fmaxf(mstar, v.x);
        }
    }
    float L = 0.f;
    float wgt[4];
#pragma unroll
    for (int i = 0; i < 4; i++) {
        wgt[i] = (i < S) ? exp2f(m[i] - mstar) : 0.f;
        L += wgt[i] * l[i];
    }
    float acc[16] = {};
#pragma unroll
    for (int i = 0; i < 4; i++) {
        if (i < S) {
            const unsigned short* P =
                Opart + (size_t)(slotbase + i) * 4096 + q * 64 + dq;
            int4 a0 = *(const int4*)P;
            int4 a1 = *(const int4*)(P + 8);
            unsigned u[8] = {(unsigned)a0.x, (unsigned)a0.y, (unsigned)a0.z,
                             (unsigned)a0.w, (unsigned)a1.x, (unsigned)a1.y,
                             (unsigned)a1.z, (unsigned)a1.w};
            float wi = wgt[i];
#pragma unroll
            for (int j = 0; j < 8; j++) {
                acc[2 * j]     += wi * bf2f((unsigned short)(u[j] & 0xFFFF));
                acc[2 * j + 1] += wi * bf2f((unsigned short)(u[j] >> 16));
            }
        }
    }
    float invL = 1.0f / L;
    int4 o0, o1;
    o0.x = cvt_pk_bf16(acc[0] * invL, acc[1] * invL);
    o0.y = cvt_pk_bf16(acc[2] * invL, acc[3] * invL);
    o0.z = cvt_pk_bf16(acc[4] * invL, acc[5] * invL);
    o0.w = cvt_pk_bf16(acc[6] * invL, acc[7] * invL);
    o1.x = cvt_pk_bf16(acc[8] * invL, acc[9] * invL);
    o1.y = cvt_pk_bf16(acc[10] * invL, acc[11] * invL);
    o1.z = cvt_pk_bf16(acc[12] * invL, acc[13] * invL);
    o1.w = cvt_pk_bf16(acc[14] * invL, acc[15] * invL);
    unsigned short* dst =
        Ob + (size_t)(b * 2048 + qt * 64 + q) * 1024 + h * 64 + dq;
    *(int4*)dst = o0;
    *(int4*)(dst + 8) = o1;
}

// ------------------------------------------------------------- output GEMM
// Same 2-phase pipelined structure as gemm_qkv.
__global__ __launch_bounds__(256) void gemm_out_kernel(
    const unsigned short* __restrict__ ab, const unsigned short* __restrict__ wot,
    float* __restrict__ out) {
    __shared__ char smem[32768];
    const int tid = threadIdx.x;
    const int lane = tid & 63, w = tid >> 6;
    const int wm = w >> 1, wn = w & 1;
    const int m0 = blockIdx.y * 128, n0 = blockIdx.x * 128;
    const int l15 = lane & 15, g = lane >> 4;

    const int srow = tid >> 2;
    const int sc0 = (tid & 3) ^ swzf2(srow);
    const int sc1 = (tid & 3) ^ swzf2(srow + 64);
    const unsigned short* aRow0 = ab + (size_t)(m0 + srow) * 1024 + sc0 * 8;
    const unsigned short* aRow1 = ab + (size_t)(m0 + srow + 64) * 1024 + sc1 * 8;
    const unsigned short* bRow0 = wot + (size_t)(n0 + srow) * 1024 + sc0 * 8;
    const unsigned short* bRow1 = wot + (size_t)(n0 + srow + 64) * 1024 + sc1 * 8;

    int aOff[4], bOff[4];
#pragma unroll
    for (int fm = 0; fm < 4; fm++) {
        int row = wm * 64 + fm * 16 + l15;
        aOff[fm] = row * 64 + ((g ^ swzf2(row)) << 4);
    }
#pragma unroll
    for (int fn = 0; fn < 4; fn++) {
        int row = wn * 64 + fn * 16 + l15;
        bOff[fn] = 0x4000 + row * 64 + ((g ^ swzf2(row)) << 4);
    }

    f32x4 acc[4][4] = {};
    GLDS16(aRow0, smem + tid * 16);
    GLDS16(aRow1, smem + tid * 16 + 4096);
    GLDS16(bRow0, smem + 0x4000 + tid * 16);
    GLDS16(bRow1, smem + 0x4000 + tid * 16 + 4096);
    asm volatile("s_waitcnt vmcnt(0)" ::: "memory");
    __builtin_amdgcn_s_barrier();

    for (int kt = 0; kt < 32; kt++) {
        const int cur = (kt & 1) << 13;
        if (kt < 31) {
            const int nxt = cur ^ 0x2000;
            GLDS16(aRow0 + (kt + 1) * 32, smem + nxt + tid * 16);
            GLDS16(aRow1 + (kt + 1) * 32, smem + nxt + tid * 16 + 4096);
            GLDS16(bRow0 + (kt + 1) * 32, smem + 0x4000 + nxt + tid * 16);
            GLDS16(bRow1 + (kt + 1) * 32, smem + 0x4000 + nxt + tid * 16 + 4096);
        }
        bshort8 af[4], bf[4];
#pragma unroll
        for (int fm = 0; fm < 4; fm++)
            af[fm] = *(const bshort8*)(smem + cur + aOff[fm]);
#pragma unroll
        for (int fn = 0; fn < 4; fn++)
            bf[fn] = *(const bshort8*)(smem + cur + bOff[fn]);
        asm volatile("s_waitcnt lgkmcnt(0)" ::: "memory");
        __builtin_amdgcn_sched_barrier(0);
#pragma unroll
        for (int fm = 0; fm < 4; fm++)
#pragma unroll
            for (int fn = 0; fn < 4; fn++)
                acc[fm][fn] = __builtin_amdgcn_mfma_f32_16x16x32_bf16(
                    af[fm], bf[fn], acc[fm][fn], 0, 0, 0);
        if (kt < 31) {
            asm volatile("s_waitcnt vmcnt(0)" ::: "memory");
            __builtin_amdgcn_s_barrier();
        }
    }
#pragma unroll
    for (int fm = 0; fm < 4; fm++)
#pragma unroll
        for (int r = 0; r < 4; r++) {
            int m = m0 + wm * 64 + fm * 16 + g * 4 + r;
#pragma unroll
            for (int fn = 0; fn < 4; fn++) {
                int n = n0 + wn * 64 + fn * 16 + l15;
                out[(size_t)m * 1024 + n] = acc[fm][fn][r];
            }
        }
}

// ---------------------------------------------------------------- launch

extern "C" void kernel_launch(void* const* d_in, const int* in_sizes, int n_in,
                              void* d_out, int out_size, void* d_ws, size_t ws_size,
                              hipStream_t stream) {
    const float* x = (const float*)d_in[0];
    const float* wq = (const float*)d_in[1];
    const float* wk = (const float*)d_in[2];
    const float* wv = (const float*)d_in[3];
    const float* wo = (const float*)d_in[4];
    float* out = (float*)d_out;
    char* ws = (char*)d_ws;

    unsigned short* xb = (unsigned short*)(ws);                  // 8 MB (later Ob)
    unsigned short* wt = (unsigned short*)(ws + 8388608);        // 3 MB (later ml)
    float* ml = (float*)(ws + 8388608);                          // 1.31 MB
    unsigned short* wot = (unsigned short*)(ws + 11534336);      // 2 MB
    float2* cs = (float2*)(ws + 13631488);                       // 0.5 MB
    unsigned short* Qb = (unsigned short*)(ws + 14155776);       // 8 MB
    unsigned short* Kb = (unsigned short*)(ws + 22544384);       // 2 MB
    unsigned short* Vb = (unsigned short*)(ws + 24641536);       // 2 MB
    unsigned short* Vtr = (unsigned short*)(ws + 26738688);      // 2 MB
    unsigned short* Opart = (unsigned short*)(ws + 28835840);    // 21 MB
    unsigned short* Ob = xb;                                     // reuse xb region

    hipLaunchKernelGGL(cast_x_kernel, dim3(2048), dim3(256), 0, stream, x, xb,
                       4194304 / 4);
    hipLaunchKernelGGL(transpose_all_kernel, dim3(32, 32, 4), dim3(32, 8), 0,
                       stream, wq, wk, wv, wo, wt, wot);
    hipLaunchKernelGGL(rope_table_kernel, dim3(256), dim3(256), 0, stream, cs);
    hipLaunchKernelGGL(gemm_qkv_kernel, dim3(12, 32), dim3(256), 0, stream, xb, wt,
                       cs, Qb, Kb, Vb);
    hipLaunchKernelGGL(transpose_v_kernel, dim3(32, 8), dim3(32, 8), 0, stream, Vb,
                       Vtr);
    hipLaunchKernelGGL(attn_kernel, dim3(80, 16, 2), dim3(256), 0, stream, Qb, Kb,
                       Vtr, Opart, ml);
    hipLaunchKernelGGL(combine_kernel, dim3(32, 16, 2), dim3(256), 0, stream,
                       Opart, ml, Ob);
    hipLaunchKernelGGL(gemm_out_kernel, dim3(8, 32), dim3(256), 0, stream, Ob, wot,
                       out);
}